// Round 6
// baseline (1353.192 us; speedup 1.0000x reference)
//
#include <hip/hip_runtime.h>

// Problem constants (from reference)
#define TV_ 2048
#define NB_ 16
#define NV_ 1024
#define TK_ 2048
#define NK_ 1024

typedef float    f32x4 __attribute__((ext_vector_type(4)));
typedef float    fl4   __attribute__((ext_vector_type(4)));
typedef _Float16 hfx8  __attribute__((ext_vector_type(8)));

static __device__ __forceinline__ ushort f2h(float f){
  _Float16 h = (_Float16)f;               // RN-even
  return __builtin_bit_cast(ushort, h);
}

// ---------------- elementwise convert: fp32 -> fp16 ----------------
__global__ __launch_bounds__(256) void cvt_h_k(const float* __restrict__ x,
                                               ushort* __restrict__ y, long n4){
  long i = (long)blockIdx.x*256 + threadIdx.x;
  const long stride = (long)gridDim.x*256;
  for (; i < n4; i += stride){
    fl4 v = ((const fl4*)x)[i];
    ((ushort4*)y)[i] = make_ushort4(f2h(v[0]), f2h(v[1]), f2h(v[2]), f2h(v[3]));
  }
}

// ---------------- w [K,V] -> wT [V,K] fp16 ----------------
__global__ void wtrans_k(const float* __restrict__ w, ushort* __restrict__ wT){
  __shared__ float t[32][33];
  const int tx = threadIdx.x, ty = threadIdx.y;       // 32 x 8
  const int k0 = blockIdx.x*32, v0 = blockIdx.y*32;
#pragma unroll
  for (int r=0;r<4;++r) t[ty+8*r][tx] = w[(long)(k0+ty+8*r)*NV_ + v0+tx];
  __syncthreads();
#pragma unroll
  for (int r=0;r<4;++r)
    wT[(long)(v0+ty+8*r)*NK_ + k0+tx] = f2h(t[tx][ty+8*r]);
}

// ------- values [Tv,B,V] -> v2 [B,Tv,V] fp16 AND vbt [B,V,Tv] fp16, one read -------
__global__ void vboth_k(const float* __restrict__ vals,
                        ushort* __restrict__ v2, ushort* __restrict__ vbt){
  __shared__ float t[32][33];
  const int tx = threadIdx.x, ty = threadIdx.y;       // 32 x 8
  const int s0 = blockIdx.x*32, v0 = blockIdx.y*32, b = blockIdx.z;
#pragma unroll
  for (int r=0;r<4;++r){
    float x = vals[((long)(s0+ty+8*r)*NB_ + b)*NV_ + v0+tx];
    t[ty+8*r][tx] = x;
    v2[((long)b*TV_ + s0+ty+8*r)*NV_ + v0+tx] = f2h(x);
  }
  __syncthreads();
#pragma unroll
  for (int r=0;r<4;++r)
    vbt[((long)b*NV_ + v0+ty+8*r)*TV_ + s0+tx] = f2h(t[tx][ty+8*r]);
}

// =======================================================================
// Shared 256x256 8-phase machinery (verified in R4; bit-identical MFMA order).
// =======================================================================
static __device__ __forceinline__ hfx8 ldfrag(const ushort* base, int r, int q){
  const int off = r*128 + (((q ^ (r & 7)) & 7) << 4);
  return *(const hfx8*)((const char*)base + off);
}

#define SAOFF(b,h) (((b)*2+(h))*8192)
#define SBOFF(b,h) (32768 + ((b)*2+(h))*8192)

#define STAGE(Xp, hb, t, ldsoff) do { \
  _Pragma("unroll") \
  for (int c_=0;c_<2;++c_) \
    __builtin_amdgcn_global_load_lds( \
      (const __attribute__((address_space(1))) unsigned*)((Xp) + (long)(hb)*128*K + (long)(t)*64 + soff[c_]), \
      (__attribute__((address_space(3))) unsigned*)(lds + (ldsoff) + chunk0[c_]*8), 16, 0, 0); \
} while(0)

#define VM4 asm volatile("s_waitcnt vmcnt(4)" ::: "memory")
#define VM0 asm volatile("s_waitcnt vmcnt(0)" ::: "memory")
#define NOPS (void)0

#define BARR() do { __builtin_amdgcn_s_barrier(); __builtin_amdgcn_sched_barrier(0); } while(0)

#define MFMA_SET(IB, JB, BREG) \
  _Pragma("unroll") for (int kk=0;kk<2;++kk) \
  _Pragma("unroll") for (int i=0;i<4;++i) \
  _Pragma("unroll") for (int j=0;j<2;++j) \
    acc[(IB)+i][(JB)+j] = __builtin_amdgcn_mfma_f32_16x16x32_f16(aR[i][kk], BREG[j][kk], acc[(IB)+i][(JB)+j], 0,0,0)

// One K-tile = 4 phases. S0..S3: stage statements; EW: end wait (vmcnt) at PH3.
#define KTILE(BUF, S0, S1, S2, S3, EW) do { \
  const ushort* sa_ = lds + SAOFF(BUF, wr); \
  const ushort* sb_ = lds + SBOFF(BUF, (wc>>1)); \
  const int brow_ = (wc&1)*64; \
  /* PH0: read a[0..3], b01 ; mfma acc[0..3][0..1] */ \
  _Pragma("unroll") for (int i=0;i<4;++i) _Pragma("unroll") for (int kk=0;kk<2;++kk) \
    aR[i][kk] = ldfrag(sa_, i*16+lm, lq+kk*4); \
  _Pragma("unroll") for (int j=0;j<2;++j) _Pragma("unroll") for (int kk=0;kk<2;++kk) \
    b01[j][kk] = ldfrag(sb_, brow_ + j*16 + lm, lq+kk*4); \
  S0; \
  BARR(); \
  __builtin_amdgcn_s_setprio(1); \
  MFMA_SET(0, 0, b01); \
  __builtin_amdgcn_s_setprio(0); \
  BARR(); \
  /* PH1: read b23 ; mfma acc[0..3][2..3] */ \
  _Pragma("unroll") for (int j=0;j<2;++j) _Pragma("unroll") for (int kk=0;kk<2;++kk) \
    b23[j][kk] = ldfrag(sb_, brow_ + (2+j)*16 + lm, lq+kk*4); \
  S1; \
  BARR(); \
  __builtin_amdgcn_s_setprio(1); \
  MFMA_SET(0, 2, b23); \
  __builtin_amdgcn_s_setprio(0); \
  BARR(); \
  /* PH2: read a[4..7] ; mfma acc[4..7][2..3] */ \
  _Pragma("unroll") for (int i=0;i<4;++i) _Pragma("unroll") for (int kk=0;kk<2;++kk) \
    aR[i][kk] = ldfrag(sa_, (4+i)*16+lm, lq+kk*4); \
  S2; \
  BARR(); \
  __builtin_amdgcn_s_setprio(1); \
  MFMA_SET(4, 2, b23); \
  __builtin_amdgcn_s_setprio(0); \
  BARR(); \
  /* PH3: (b01 cached) ; mfma acc[4..7][0..1] */ \
  S3; \
  BARR(); \
  __builtin_amdgcn_s_setprio(1); \
  MFMA_SET(4, 0, b01); \
  __builtin_amdgcn_s_setprio(0); \
  EW; \
  BARR(); \
} while(0)

// ---------------- generic GEMM (GEMM1, GEMM2, fallback GEMM3) ----------------
// SMPART=1: epilogue also emits per-wave row (max, sum-exp) partials for softmax.
template<int OUTF16, int SMPART>
__global__ __launch_bounds__(512, 2)
void gemm8_k(const ushort* __restrict__ A, const ushort* __restrict__ BT,
             float* __restrict__ C, ushort* __restrict__ Ch,
             float* __restrict__ pm, float* __restrict__ ps,
             int N, int K, long sA, long sB, long sC)
{
  extern __shared__ ushort lds[];

  const int tid  = threadIdx.x;
  const int lane = tid & 63;
  const int w    = tid >> 6;
  const int wr   = w >> 2;
  const int wc   = w & 3;
  const int lm   = lane & 15, lq = lane >> 4;
  const int bz   = blockIdx.z;
  const long m0  = (long)blockIdx.y * 256;
  const long n0  = (long)blockIdx.x * 256;

  const ushort* Ap = A  + (long)bz*sA + m0*K;
  const ushort* Bp = BT + (long)bz*sB + n0*K;

  int chunk0[2], soff[2];
#pragma unroll
  for (int c=0;c<2;++c){
    chunk0[c] = (w<<7) + (c<<6);
    const int idx = chunk0[c] + lane;
    const int row = idx >> 3, sl = idx & 7;
    soff[c] = row*K + ((sl ^ (row & 7)) << 3);
  }

  f32x4 acc[8][4];
#pragma unroll
  for (int i=0;i<8;++i)
#pragma unroll
    for (int j=0;j<4;++j) acc[i][j] = (f32x4){0.f,0.f,0.f,0.f};

  hfx8 aR[4][2], b01[2][2], b23[2][2];

  const int NT = K >> 6;

  STAGE(Ap, 0, 0, SAOFF(0,0));
  STAGE(Ap, 1, 0, SAOFF(0,1));
  STAGE(Bp, 0, 0, SBOFF(0,0));
  STAGE(Bp, 1, 0, SBOFF(0,1));
  STAGE(Bp, 0, 1, SBOFF(1,0));
  STAGE(Ap, 0, 1, SAOFF(1,0));
  VM4;
  BARR();

  for (int u=0; u <= NT-4; u+=2){
    KTILE(0,
          STAGE(Ap, 1, u+1, SAOFF(1,1)),
          STAGE(Bp, 1, u+1, SBOFF(1,1)),
          STAGE(Bp, 0, u+2, SBOFF(0,0)),
          STAGE(Ap, 0, u+2, SAOFF(0,0)),
          VM4);
    KTILE(1,
          STAGE(Ap, 1, u+2, SAOFF(0,1)),
          STAGE(Bp, 1, u+2, SBOFF(0,1)),
          STAGE(Bp, 0, u+3, SBOFF(1,0)),
          STAGE(Ap, 0, u+3, SAOFF(1,0)),
          VM4);
  }
  KTILE(0,
        STAGE(Ap, 1, NT-1, SAOFF(1,1)),
        STAGE(Bp, 1, NT-1, SBOFF(1,1)),
        NOPS, NOPS, VM0);
  KTILE(1, NOPS, NOPS, NOPS, NOPS, NOPS);

  if constexpr (SMPART){
    // per-wave (64-col) row max & sum-exp partials; partial idx = bx*4 + wc
#pragma unroll
    for (int i=0;i<8;++i)
#pragma unroll
      for (int g=0; g<4; ++g){
        float mt = fmaxf(fmaxf(acc[i][0][g], acc[i][1][g]), fmaxf(acc[i][2][g], acc[i][3][g]));
#pragma unroll
        for (int off=1; off<16; off<<=1) mt = fmaxf(mt, __shfl_xor(mt, off));
        float se = 0.f;
#pragma unroll
        for (int j=0;j<4;++j) se += __expf(acc[i][j][g] - mt);
#pragma unroll
        for (int off=1; off<16; off<<=1) se += __shfl_xor(se, off);
        if (lm == 0){
          const long rg = (long)bz*TK_ + m0 + wr*128 + i*16 + lq*4 + g;
          pm[rg*32 + blockIdx.x*4 + wc] = mt;
          ps[rg*32 + blockIdx.x*4 + wc] = se;
        }
      }
  }

  const long cb = (long)bz*sC;
#pragma unroll
  for (int i=0;i<8;++i)
#pragma unroll
    for (int j=0;j<4;++j)
#pragma unroll
      for (int g=0; g<4; ++g){
        const long gm = m0 + wr*128 + i*16 + lq*4 + g;
        const long gn = n0 + wc*64  + j*16 + lm;
        const long o = cb + gm*N + gn;
        if constexpr (OUTF16) Ch[o] = f2h(acc[i][j][g]);
        else                  C[o]  = acc[i][j][g];
      }
}

// ---------------- row-stat reduce: 32 partials -> m, 1/s per row ----------------
__global__ __launch_bounds__(256) void rs_k(const float* __restrict__ pm,
                                            const float* __restrict__ ps,
                                            float* __restrict__ mrow,
                                            float* __restrict__ isrow){
  const long r = (long)blockIdx.x*256 + threadIdx.x;   // 32768 rows total
  float m = -3.4e38f;
#pragma unroll
  for (int p=0;p<32;++p) m = fmaxf(m, pm[r*32+p]);
  float s = 0.f;
#pragma unroll
  for (int p=0;p<32;++p) s += ps[r*32+p] * __expf(pm[r*32+p] - m);
  mrow[r] = m;
  isrow[r] = 1.f/s;
}

// ---------------- fused softmax + PV GEMM ----------------
// A = exp(logits - m)*invs computed in-register from fp32 logits (reg-staged,
// T14 split: loads issued one phase before convert+ds_write); B = vbt via
// global_load_lds. WR=1 blocks (bx quarter 0) also write attn fp32.
// Manual vmcnt eliminated: each WRA's compiler-inserted wait (before exp use)
// retires all older vm ops, which the ledger shows covers every B half-tile
// before its consumer tile.
#define LDA(h, t) do { \
  _Pragma("unroll") for (int c_=0;c_<4;++c_) \
    aSt[c_] = *(const fl4*)(Alg + ((long)((h)*128 + arow[c_]))*TV_ + (long)(t)*64 + acol4[c_]*4); \
} while(0)

#define WRA(h, t, ldso) do { \
  _Pragma("unroll") for (int c_=0;c_<4;++c_){ \
    fl4 pf; \
    _Pragma("unroll") for (int q_=0;q_<4;++q_) \
      pf[q_] = __expf(aSt[c_][q_] - mreg[(h)*4+c_]) * isreg[(h)*4+c_]; \
    if constexpr (WR) \
      *(fl4*)(Pat + ((long)((h)*128 + arow[c_]))*TV_ + (long)(t)*64 + acol4[c_]*4) = pf; \
    const int slot_ = acol4[c_] >> 1; \
    const int bo_ = arow[c_]*128 + (((slot_ ^ (arow[c_] & 7)) & 7) << 4) + (acol4[c_] & 1)*8; \
    *(ushort4*)((char*)lds + (long)(ldso)*2 + bo_) = \
        make_ushort4(f2h(pf[0]), f2h(pf[1]), f2h(pf[2]), f2h(pf[3])); \
  } \
  asm volatile("s_waitcnt lgkmcnt(0)" ::: "memory"); \
} while(0)

#define PVS1(t, sbo, sao) do { STAGE(Bp, 1, t, sbo); WRA(1, t, sao); } while(0)
#define PVS2(t, sbo)      do { LDA(0, t); STAGE(Bp, 0, t, sbo); } while(0)
#define PVS3(t, sao)      do { WRA(0, t, sao); } while(0)

template<int WR>
__global__ __launch_bounds__(512, 2)
void pv_fused_k(const float* __restrict__ lgits, const ushort* __restrict__ vbt,
                const float* __restrict__ mrow, const float* __restrict__ isrow,
                float* __restrict__ attn, float* __restrict__ outp, int n0off)
{
  extern __shared__ ushort lds[];

  const int tid  = threadIdx.x;
  const int lane = tid & 63;
  const int w    = tid >> 6;
  const int wr   = w >> 2;
  const int wc   = w & 3;
  const int lm   = lane & 15, lq = lane >> 4;
  const int bz   = blockIdx.z;
  const long m0  = (long)blockIdx.y * 256;
  const long n0  = (long)(blockIdx.x + n0off) * 256;
  const int K    = TV_;                    // PV contraction dim
  const int NT   = K >> 6;                 // 32

  const float*  Alg = lgits + (long)bz*TK_*TV_ + m0*TV_;
  float*        Pat = attn  + (long)bz*TK_*TV_ + m0*TV_;
  const ushort* Bp  = vbt   + (long)bz*NV_*TV_ + n0*TV_;

  // B staging offsets (as in gemm8_k)
  int chunk0[2], soff[2];
#pragma unroll
  for (int c=0;c<2;++c){
    chunk0[c] = (w<<7) + (c<<6);
    const int idx = chunk0[c] + lane;
    const int row = idx >> 3, sl = idx & 7;
    soff[c] = row*K + ((sl ^ (row & 7)) << 3);
  }
  // A staging coords: fp32 half-tile [128][64], 4 x 16B chunks per thread
  int arow[4], acol4[4];
#pragma unroll
  for (int c=0;c<4;++c){
    const int idx = (w<<8) + (c<<6) + lane;
    arow[c]  = idx >> 4;
    acol4[c] = idx & 15;
  }
  // per-row softmax stats for this thread's staged rows (const over K)
  float mreg[8], isreg[8];
#pragma unroll
  for (int h=0;h<2;++h)
#pragma unroll
    for (int c=0;c<4;++c){
      const long rg = (long)bz*TK_ + m0 + h*128 + arow[c];
      mreg[h*4+c]  = mrow[rg];
      isreg[h*4+c] = isrow[rg];
    }

  f32x4 acc[8][4];
#pragma unroll
  for (int i=0;i<8;++i)
#pragma unroll
    for (int j=0;j<4;++j) acc[i][j] = (f32x4){0.f,0.f,0.f,0.f};

  hfx8 aR[4][2], b01[2][2], b23[2][2];
  fl4  aSt[4];

  // Prologue: tile0 A (via reg+exp), tile0 B, tile1 A0, tile1 B0 in flight
  LDA(0,0); WRA(0,0, SAOFF(0,0));
  LDA(1,0); WRA(1,0, SAOFF(0,1));
  STAGE(Bp, 0, 0, SBOFF(0,0));
  STAGE(Bp, 1, 0, SBOFF(0,1));
  LDA(0,1); WRA(0,1, SAOFF(1,0));       // its wait retires B0(0),B1(0)
  STAGE(Bp, 0, 1, SBOFF(1,0));
  BARR();

  for (int u=0; u <= NT-4; u+=2){
    KTILE(0,
          LDA(1, u+1),
          PVS1(u+1, SBOFF(1,1), SAOFF(1,1)),
          PVS2(u+2, SBOFF(0,0)),
          PVS3(u+2, SAOFF(0,0)),
          NOPS);
    KTILE(1,
          LDA(1, u+2),
          PVS1(u+2, SBOFF(0,1), SAOFF(0,1)),
          PVS2(u+3, SBOFF(1,0)),
          PVS3(u+3, SAOFF(1,0)),
          NOPS);
  }
  KTILE(0,
        LDA(1, NT-1),
        PVS1(NT-1, SBOFF(1,1), SAOFF(1,1)),
        NOPS, NOPS, VM0);
  KTILE(1, NOPS, NOPS, NOPS, NOPS, NOPS);

  // C-write: output [B, Tk, V]
  const long cb = (long)bz*TK_*NV_;
#pragma unroll
  for (int i=0;i<8;++i)
#pragma unroll
    for (int j=0;j<4;++j)
#pragma unroll
      for (int g=0; g<4; ++g){
        const long gm = m0 + wr*128 + i*16 + lq*4 + g;
        const long gn = n0 + wc*64  + j*16 + lm;
        outp[cb + gm*NV_ + gn] = acc[i][j][g];
      }
}

// ---------------- row softmax (fallback path only) ----------------
__global__ __launch_bounds__(256) void softmax_k(float* __restrict__ lg, ushort* __restrict__ pb){
  const long base = (long)blockIdx.x * TV_;
  const int tid = threadIdx.x;
  const int lane = tid & 63, w = tid >> 6;
  float x[8];
  fl4 a = *(const fl4*)(lg + base + tid*8);
  fl4 b = *(const fl4*)(lg + base + tid*8 + 4);
  x[0]=a[0];x[1]=a[1];x[2]=a[2];x[3]=a[3];x[4]=b[0];x[5]=b[1];x[6]=b[2];x[7]=b[3];
  float m = x[0];
#pragma unroll
  for (int j=1;j<8;++j) m = fmaxf(m, x[j]);
#pragma unroll
  for (int off=32; off; off>>=1) m = fmaxf(m, __shfl_xor(m, off));
  __shared__ float rm[4], rs[4];
  if (lane==0) rm[w]=m;
  __syncthreads();
  m = fmaxf(fmaxf(rm[0],rm[1]), fmaxf(rm[2],rm[3]));
  float s = 0.f;
#pragma unroll
  for (int j=0;j<8;++j){ x[j] = __expf(x[j]-m); s += x[j]; }
#pragma unroll
  for (int off=32; off; off>>=1) s += __shfl_xor(s, off);
  if (lane==0) rs[w]=s;
  __syncthreads();
  s = rs[0]+rs[1]+rs[2]+rs[3];
  const float inv = 1.f/s;
  fl4 p0 = {x[0]*inv, x[1]*inv, x[2]*inv, x[3]*inv};
  fl4 p1 = {x[4]*inv, x[5]*inv, x[6]*inv, x[7]*inv};
  *(fl4*)(lg + base + tid*8)     = p0;
  *(fl4*)(lg + base + tid*8 + 4) = p1;
  *(ushort4*)(pb + base + tid*8)     = make_ushort4(f2h(p0[0]),f2h(p0[1]),f2h(p0[2]),f2h(p0[3]));
  *(ushort4*)(pb + base + tid*8 + 4) = make_ushort4(f2h(p1[0]),f2h(p1[1]),f2h(p1[2]),f2h(p1[3]));
}

extern "C" void kernel_launch(void* const* d_in, const int* in_sizes, int n_in,
                              void* d_out, int out_size, void* d_ws, size_t ws_size,
                              hipStream_t stream){
  (void)in_sizes; (void)n_in; (void)out_size;
  const float* values = (const float*)d_in[0];   // [Tv,B,V]
  const float* keys   = (const float*)d_in[2];   // [B,Tk,K]
  const float* w      = (const float*)d_in[3];   // [K,V]

  float* attn = (float*)d_out;                       // [B,Tk,Tv]
  float* outp = (float*)d_out + (long)NB_*TK_*TV_;   // [B,Tk,V]

  char* ws = (char*)d_ws;
  const long MB = 1024L*1024L;
  const bool fused = ws_size >= (size_t)(460*MB);

  ushort* kh   = (ushort*)(ws);                // 64MB keys fp16 (reused: v2)
  ushort* vbt  = (ushort*)(ws + 64*MB);        // 64MB vbt [B,V,Tv] fp16
  ushort* plh  = (ushort*)(ws + 128*MB);       // 64MB pl fp16
  ushort* adb  = (ushort*)(ws + 128*MB);       // fallback: 128MB attn fp16
  float*  lgts = (float*)(ws + 192*MB);        // fused: 256MB logits fp32
  ushort* wth  = (ushort*)(ws + (fused ? 448 : 256)*MB);  // 2MB wT fp16
  float*  pm   = (float*)(ws + 450*MB);        // 4MB partial max
  float*  psum = (float*)(ws + 454*MB);        // 4MB partial sum-exp
  float*  mrow = (float*)(ws + 458*MB);        // 128KB row max
  float*  isrw = (float*)(ws + 458*MB + 256*1024);  // 128KB row 1/s
  ushort* v2   = kh;

  const size_t LDSB = 131072;

  // 1) keys -> fp16
  cvt_h_k<<<2048,256,0,stream>>>(keys, kh, (long)NB_*TK_*NK_/4);
  // 2) w -> wT fp16
  wtrans_k<<<dim3(32,32),dim3(32,8),0,stream>>>(w, wth);
  // 3) GEMM1: pl = keys * w -> fp16 [B,Tk,V]
  gemm8_k<1,0><<<dim3(NV_/256, TK_/256, NB_),512,LDSB,stream>>>(
      kh, wth, nullptr, plh, nullptr, nullptr,
      NV_, NK_, (long)TK_*NK_, 0L, (long)TK_*NV_);
  // 4) v2 [B,Tv,V] + vbt [B,V,Tv] fp16 (v2 reuses keys space; after GEMM1)
  vboth_k<<<dim3(TV_/32, NV_/32, NB_),dim3(32,8),0,stream>>>(values, v2, vbt);

  if (fused){
    // 5) GEMM2: logits -> ws, + per-wave softmax partials
    gemm8_k<0,1><<<dim3(TV_/256, TK_/256, NB_),512,LDSB,stream>>>(
        plh, v2, lgts, nullptr, pm, psum,
        TV_, NV_, (long)TK_*NV_, (long)TV_*NV_, (long)TK_*TV_);
    // 6) reduce partials -> per-row m, 1/s
    rs_k<<<NB_*TK_/256,256,0,stream>>>(pm, psum, mrow, isrw);
    // 7) fused softmax + PV; bx-quarter 0 also writes attn fp32
    pv_fused_k<1><<<dim3(1, TK_/256, NB_),512,LDSB,stream>>>(
        lgts, vbt, mrow, isrw, attn, outp, 0);
    pv_fused_k<0><<<dim3(3, TK_/256, NB_),512,LDSB,stream>>>(
        lgts, vbt, mrow, isrw, attn, outp, 1);
  } else {
    // Fallback: exact R4 path
    gemm8_k<0,0><<<dim3(TV_/256, TK_/256, NB_),512,LDSB,stream>>>(
        plh, v2, attn, nullptr, nullptr, nullptr,
        TV_, NV_, (long)TK_*NV_, (long)TV_*NV_, (long)TK_*TV_);
    softmax_k<<<NB_*TK_,256,0,stream>>>(attn, adb);
    gemm8_k<0,0><<<dim3(NV_/256, TK_/256, NB_),512,LDSB,stream>>>(
        adb, vbt, outp, nullptr, nullptr, nullptr,
        NV_, TV_, (long)TK_*TV_, (long)NV_*TV_, (long)TK_*NV_);
  }
}

// Round 7
// 815.675 us; speedup vs baseline: 1.6590x; 1.6590x over previous
//
#include <hip/hip_runtime.h>

// Problem constants (from reference)
#define TV_ 2048
#define NB_ 16
#define NV_ 1024
#define TK_ 2048
#define NK_ 1024

typedef float    f32x4 __attribute__((ext_vector_type(4)));
typedef float    fl4   __attribute__((ext_vector_type(4)));
typedef _Float16 hfx8  __attribute__((ext_vector_type(8)));
typedef ushort   us8   __attribute__((ext_vector_type(8)));

static __device__ __forceinline__ ushort f2h(float f){
  _Float16 h = (_Float16)f;               // RN-even
  return __builtin_bit_cast(ushort, h);
}
static __device__ __forceinline__ float h2f(ushort u){
  return (float)__builtin_bit_cast(_Float16, u);
}

// ---------------- elementwise convert: fp32 -> fp16 ----------------
__global__ __launch_bounds__(256) void cvt_h_k(const float* __restrict__ x,
                                               ushort* __restrict__ y, long n4){
  long i = (long)blockIdx.x*256 + threadIdx.x;
  const long stride = (long)gridDim.x*256;
  for (; i < n4; i += stride){
    fl4 v = ((const fl4*)x)[i];
    ((ushort4*)y)[i] = make_ushort4(f2h(v[0]), f2h(v[1]), f2h(v[2]), f2h(v[3]));
  }
}

// ---------------- w [K,V] -> wT [V,K] fp16 ----------------
__global__ void wtrans_k(const float* __restrict__ w, ushort* __restrict__ wT){
  __shared__ float t[32][33];
  const int tx = threadIdx.x, ty = threadIdx.y;       // 32 x 8
  const int k0 = blockIdx.x*32, v0 = blockIdx.y*32;
#pragma unroll
  for (int r=0;r<4;++r) t[ty+8*r][tx] = w[(long)(k0+ty+8*r)*NV_ + v0+tx];
  __syncthreads();
#pragma unroll
  for (int r=0;r<4;++r)
    wT[(long)(v0+ty+8*r)*NK_ + k0+tx] = f2h(t[tx][ty+8*r]);
}

// ------- values [Tv,B,V] -> v2 [B,Tv,V] fp16 AND vbt [B,V,Tv] fp16, one read -------
__global__ void vboth_k(const float* __restrict__ vals,
                        ushort* __restrict__ v2, ushort* __restrict__ vbt){
  __shared__ float t[32][33];
  const int tx = threadIdx.x, ty = threadIdx.y;       // 32 x 8
  const int s0 = blockIdx.x*32, v0 = blockIdx.y*32, b = blockIdx.z;
#pragma unroll
  for (int r=0;r<4;++r){
    float x = vals[((long)(s0+ty+8*r)*NB_ + b)*NV_ + v0+tx];
    t[ty+8*r][tx] = x;
    v2[((long)b*TV_ + s0+ty+8*r)*NV_ + v0+tx] = f2h(x);
  }
  __syncthreads();
#pragma unroll
  for (int r=0;r<4;++r)
    vbt[((long)b*NV_ + v0+ty+8*r)*TV_ + s0+tx] = f2h(t[tx][ty+8*r]);
}

// =======================================================================
// Shared 256x256 8-phase machinery (verified R4; MFMA order bit-stable).
// =======================================================================
static __device__ __forceinline__ hfx8 ldfrag(const ushort* base, int r, int q){
  const int off = r*128 + (((q ^ (r & 7)) & 7) << 4);
  return *(const hfx8*)((const char*)base + off);
}

#define SAOFF(b,h) (((b)*2+(h))*8192)
#define SBOFF(b,h) (32768 + ((b)*2+(h))*8192)

#define STAGE(Xp, hb, t, ldsoff) do { \
  _Pragma("unroll") \
  for (int c_=0;c_<2;++c_) \
    __builtin_amdgcn_global_load_lds( \
      (const __attribute__((address_space(1))) unsigned*)((Xp) + (long)(hb)*128*K + (long)(t)*64 + soff[c_]), \
      (__attribute__((address_space(3))) unsigned*)(lds + (ldsoff) + chunk0[c_]*8), 16, 0, 0); \
} while(0)

#define VM4  asm volatile("s_waitcnt vmcnt(4)"  ::: "memory")
#define VM10 asm volatile("s_waitcnt vmcnt(10)" ::: "memory")
#define VM0  asm volatile("s_waitcnt vmcnt(0)"  ::: "memory")
#define NOPS (void)0

#define BARR() do { __builtin_amdgcn_s_barrier(); __builtin_amdgcn_sched_barrier(0); } while(0)

#define MFMA_SET(IB, JB, BREG) \
  _Pragma("unroll") for (int kk=0;kk<2;++kk) \
  _Pragma("unroll") for (int i=0;i<4;++i) \
  _Pragma("unroll") for (int j=0;j<2;++j) \
    acc[(IB)+i][(JB)+j] = __builtin_amdgcn_mfma_f32_16x16x32_f16(aR[i][kk], BREG[j][kk], acc[(IB)+i][(JB)+j], 0,0,0)

// One K-tile = 4 phases. S0..S3: stage statements; EW: end wait (vmcnt) at PH3.
#define KTILE(BUF, S0, S1, S2, S3, EW) do { \
  const ushort* sa_ = lds + SAOFF(BUF, wr); \
  const ushort* sb_ = lds + SBOFF(BUF, (wc>>1)); \
  const int brow_ = (wc&1)*64; \
  /* PH0 */ \
  _Pragma("unroll") for (int i=0;i<4;++i) _Pragma("unroll") for (int kk=0;kk<2;++kk) \
    aR[i][kk] = ldfrag(sa_, i*16+lm, lq+kk*4); \
  _Pragma("unroll") for (int j=0;j<2;++j) _Pragma("unroll") for (int kk=0;kk<2;++kk) \
    b01[j][kk] = ldfrag(sb_, brow_ + j*16 + lm, lq+kk*4); \
  S0; \
  BARR(); \
  __builtin_amdgcn_s_setprio(1); \
  MFMA_SET(0, 0, b01); \
  __builtin_amdgcn_s_setprio(0); \
  BARR(); \
  /* PH1 */ \
  _Pragma("unroll") for (int j=0;j<2;++j) _Pragma("unroll") for (int kk=0;kk<2;++kk) \
    b23[j][kk] = ldfrag(sb_, brow_ + (2+j)*16 + lm, lq+kk*4); \
  S1; \
  BARR(); \
  __builtin_amdgcn_s_setprio(1); \
  MFMA_SET(0, 2, b23); \
  __builtin_amdgcn_s_setprio(0); \
  BARR(); \
  /* PH2 */ \
  _Pragma("unroll") for (int i=0;i<4;++i) _Pragma("unroll") for (int kk=0;kk<2;++kk) \
    aR[i][kk] = ldfrag(sa_, (4+i)*16+lm, lq+kk*4); \
  S2; \
  BARR(); \
  __builtin_amdgcn_s_setprio(1); \
  MFMA_SET(4, 2, b23); \
  __builtin_amdgcn_s_setprio(0); \
  BARR(); \
  /* PH3 */ \
  S3; \
  BARR(); \
  __builtin_amdgcn_s_setprio(1); \
  MFMA_SET(4, 0, b01); \
  __builtin_amdgcn_s_setprio(0); \
  EW; \
  BARR(); \
} while(0)

// ---------------- generic GEMM ----------------
// OUTMODE: 0 = fp32 C; 1 = fp16 Ch; 2 = fp16 Ch shifted by per-wave 64-col max
//          + softmax partials (pm, ps).
template<int OUTMODE>
__global__ __launch_bounds__(512, 2)
void gemm8_k(const ushort* __restrict__ A, const ushort* __restrict__ BT,
             float* __restrict__ C, ushort* __restrict__ Ch,
             float* __restrict__ pm, float* __restrict__ ps,
             int N, int K, long sA, long sB, long sC)
{
  extern __shared__ ushort lds[];

  const int tid  = threadIdx.x;
  const int lane = tid & 63;
  const int w    = tid >> 6;
  const int wr   = w >> 2;
  const int wc   = w & 3;
  const int lm   = lane & 15, lq = lane >> 4;
  const int bz   = blockIdx.z;
  const long m0  = (long)blockIdx.y * 256;
  const long n0  = (long)blockIdx.x * 256;

  const ushort* Ap = A  + (long)bz*sA + m0*K;
  const ushort* Bp = BT + (long)bz*sB + n0*K;

  int chunk0[2], soff[2];
#pragma unroll
  for (int c=0;c<2;++c){
    chunk0[c] = (w<<7) + (c<<6);
    const int idx = chunk0[c] + lane;
    const int row = idx >> 3, sl = idx & 7;
    soff[c] = row*K + ((sl ^ (row & 7)) << 3);
  }

  f32x4 acc[8][4];
#pragma unroll
  for (int i=0;i<8;++i)
#pragma unroll
    for (int j=0;j<4;++j) acc[i][j] = (f32x4){0.f,0.f,0.f,0.f};

  hfx8 aR[4][2], b01[2][2], b23[2][2];

  const int NT = K >> 6;

  STAGE(Ap, 0, 0, SAOFF(0,0));
  STAGE(Ap, 1, 0, SAOFF(0,1));
  STAGE(Bp, 0, 0, SBOFF(0,0));
  STAGE(Bp, 1, 0, SBOFF(0,1));
  STAGE(Bp, 0, 1, SBOFF(1,0));
  STAGE(Ap, 0, 1, SAOFF(1,0));
  VM4;
  BARR();

  for (int u=0; u <= NT-4; u+=2){
    KTILE(0,
          STAGE(Ap, 1, u+1, SAOFF(1,1)),
          STAGE(Bp, 1, u+1, SBOFF(1,1)),
          STAGE(Bp, 0, u+2, SBOFF(0,0)),
          STAGE(Ap, 0, u+2, SAOFF(0,0)),
          VM4);
    KTILE(1,
          STAGE(Ap, 1, u+2, SAOFF(0,1)),
          STAGE(Bp, 1, u+2, SBOFF(0,1)),
          STAGE(Bp, 0, u+3, SBOFF(1,0)),
          STAGE(Ap, 0, u+3, SAOFF(1,0)),
          VM4);
  }
  KTILE(0,
        STAGE(Ap, 1, NT-1, SAOFF(1,1)),
        STAGE(Bp, 1, NT-1, SBOFF(1,1)),
        NOPS, NOPS, VM0);
  KTILE(1, NOPS, NOPS, NOPS, NOPS, NOPS);

  const long cb = (long)bz*sC;
  if constexpr (OUTMODE == 2){
#pragma unroll
    for (int i=0;i<8;++i){
      float mts[4];
#pragma unroll
      for (int g=0; g<4; ++g){
        float mt = fmaxf(fmaxf(acc[i][0][g], acc[i][1][g]), fmaxf(acc[i][2][g], acc[i][3][g]));
#pragma unroll
        for (int off=1; off<16; off<<=1) mt = fmaxf(mt, __shfl_xor(mt, off));
        float se = 0.f;
#pragma unroll
        for (int j=0;j<4;++j) se += __expf(acc[i][j][g] - mt);
#pragma unroll
        for (int off=1; off<16; off<<=1) se += __shfl_xor(se, off);
        if (lm == 0){
          const long rg = (long)bz*TK_ + m0 + wr*128 + i*16 + lq*4 + g;
          pm[rg*32 + blockIdx.x*4 + wc] = mt;
          ps[rg*32 + blockIdx.x*4 + wc] = se;
        }
        mts[g] = mt;
      }
#pragma unroll
      for (int j=0;j<4;++j)
#pragma unroll
        for (int g=0; g<4; ++g){
          const long gm = m0 + wr*128 + i*16 + lq*4 + g;
          const long gn = n0 + wc*64  + j*16 + lm;
          Ch[cb + gm*N + gn] = f2h(acc[i][j][g] - mts[g]);
        }
    }
  } else {
#pragma unroll
    for (int i=0;i<8;++i)
#pragma unroll
      for (int j=0;j<4;++j)
#pragma unroll
        for (int g=0; g<4; ++g){
          const long gm = m0 + wr*128 + i*16 + lq*4 + g;
          const long gn = n0 + wc*64  + j*16 + lm;
          const long o = cb + gm*N + gn;
          if constexpr (OUTMODE == 1) Ch[o] = f2h(acc[i][j][g]);
          else                        C[o]  = acc[i][j][g];
        }
  }
}

// ---- row-stat reduce: 32 (max,sumexp) partials -> dsh2[r][p] = mt - m - ln(s) ----
__global__ __launch_bounds__(256) void rs_k(const float* __restrict__ pm,
                                            const float* __restrict__ ps,
                                            float* __restrict__ dsh2){
  const long r = (long)blockIdx.x*256 + threadIdx.x;   // 32768 rows
  float pmv[32];
  float m = -3.4e38f;
#pragma unroll
  for (int p=0;p<32;++p){ pmv[p] = pm[r*32+p]; m = fmaxf(m, pmv[p]); }
  float s = 0.f;
#pragma unroll
  for (int p=0;p<32;++p) s += ps[r*32+p] * __expf(pmv[p] - m);
  const float lg = __logf(s);
#pragma unroll
  for (int p=0;p<32;++p) dsh2[r*32+p] = pmv[p] - m - lg;
}

// ---------------- fused softmax + PV GEMM (v2) ----------------
// A = p = exp(h + dsh2), h = fp16 shifted logits, reg-prefetched 4 phases ahead
// (2 static reg buffers aS0/aS1). B = vbt via global_load_lds (proven pattern).
// vmcnt ledger (12 vm ops/tile): WRA implicit waits land at vmcnt(8);
// EW = vmcnt(10) retires exactly the next tile's B half-tiles. bx==0 blocks
// also write attn fp32.
#define LDA_H(AREG, DREG, h, t) do { \
  _Pragma("unroll") for (int c_=0;c_<2;++c_) \
    AREG[h][c_] = *(const us8*)(aP[h][c_] + (long)(t)*64); \
  _Pragma("unroll") for (int c_=0;c_<2;++c_) \
    DREG[h][c_] = dP[h][c_][t]; \
} while(0)

#define WRA_H(AREG, DREG, h, t, ldso) do { \
  _Pragma("unroll") for (int c_=0;c_<2;++c_){ \
    us8 r_ = AREG[h][c_]; const float d_ = DREG[h][c_]; \
    float pf_[8]; \
    _Pragma("unroll") for (int e_=0;e_<8;++e_) \
      pf_[e_] = __expf(h2f((ushort)r_[e_]) + d_); \
    if (doWR){ \
      fl4 q0_ = {pf_[0],pf_[1],pf_[2],pf_[3]}; \
      fl4 q1_ = {pf_[4],pf_[5],pf_[6],pf_[7]}; \
      *(fl4*)(pP[h][c_] + (long)(t)*64)     = q0_; \
      *(fl4*)(pP[h][c_] + (long)(t)*64 + 4) = q1_; \
    } \
    us8 o_; \
    _Pragma("unroll") for (int e_=0;e_<8;++e_) o_[e_] = f2h(pf_[e_]); \
    *(us8*)((char*)lds + (long)(ldso)*2 + abo[c_]) = o_; \
  } \
  asm volatile("s_waitcnt lgkmcnt(0)" ::: "memory"); \
} while(0)

__global__ __launch_bounds__(512, 2)
void pv2_k(const ushort* __restrict__ lg16, const ushort* __restrict__ vbt,
           const float* __restrict__ dsh2,
           float* __restrict__ attn, float* __restrict__ outp)
{
  extern __shared__ ushort lds[];

  const int tid  = threadIdx.x;
  const int lane = tid & 63;
  const int w    = tid >> 6;
  const int wr   = w >> 2;
  const int wc   = w & 3;
  const int lm   = lane & 15, lq = lane >> 4;
  const int bz   = blockIdx.z;
  const long m0  = (long)blockIdx.y * 256;
  const long n0  = (long)blockIdx.x * 256;
  const bool doWR = (blockIdx.x == 0);
  const int K    = TV_;
  const int NT   = K >> 6;                 // 32

  const ushort* Alg = lg16 + ((long)bz*TK_ + m0)*TV_;
  float*        Pat = attn + ((long)bz*TK_ + m0)*TV_;
  const ushort* Bp  = vbt  + ((long)bz*NV_ + n0)*TV_;

  // B staging (identical to gemm8_k)
  int chunk0[2], soff[2];
#pragma unroll
  for (int c=0;c<2;++c){
    chunk0[c] = (w<<7) + (c<<6);
    const int idx = chunk0[c] + lane;
    const int row = idx >> 3, sl = idx & 7;
    soff[c] = row*K + ((sl ^ (row & 7)) << 3);
  }
  // A staging coords: fp16 half-tile [128][64] = 1024 x 16B chunks; 2/thread
  int arow[2], acol8[2], abo[2];
  const ushort* aP[2][2];
  float*        pP[2][2];
  const float*  dP[2][2];
#pragma unroll
  for (int c=0;c<2;++c){
    const int idx = (c<<9) + tid;
    arow[c]  = idx >> 3;
    acol8[c] = idx & 7;
    abo[c]   = arow[c]*128 + (((acol8[c] ^ (arow[c] & 7)) & 7) << 4);
#pragma unroll
    for (int h=0;h<2;++h){
      aP[h][c] = Alg + (long)(h*128 + arow[c])*TV_ + acol8[c]*8;
      pP[h][c] = Pat + (long)(h*128 + arow[c])*TV_ + acol8[c]*8;
      dP[h][c] = dsh2 + ((long)bz*TK_ + m0 + h*128 + arow[c])*32;
    }
  }

  f32x4 acc[8][4];
#pragma unroll
  for (int i=0;i<8;++i)
#pragma unroll
    for (int j=0;j<4;++j) acc[i][j] = (f32x4){0.f,0.f,0.f,0.f};

  hfx8 aR[4][2], b01[2][2], b23[2][2];
  us8   aS0[2][2], aS1[2][2];
  float dS0[2][2], dS1[2][2];

  // Prologue: tile0 A via reg+exp; tile0 B; tile1 A-regs; tile1 B0 in flight
  LDA_H(aS0, dS0, 0, 0);
  LDA_H(aS0, dS0, 1, 0);
  WRA_H(aS0, dS0, 0, 0, SAOFF(0,0));
  WRA_H(aS0, dS0, 1, 0, SAOFF(0,1));
  STAGE(Bp, 0, 0, SBOFF(0,0));
  STAGE(Bp, 1, 0, SBOFF(0,1));
  LDA_H(aS1, dS1, 0, 1);
  LDA_H(aS1, dS1, 1, 1);
  STAGE(Bp, 0, 1, SBOFF(1,0));
  VM10;      // retires tile0 B stages; keeps LDA/LDP(1)=8 + B0(1)=2 in flight
  BARR();

  for (int u=0; u <= NT-4; u+=2){
    // tile u (buf0): WRA(u+1)<-aS1, LDA(u+2)->aS0, stage B1(u+1), B0(u+2)
    KTILE(0,
          NOPS,
          STAGE(Bp, 1, u+1, SBOFF(1,1)),
          { WRA_H(aS1, dS1, 0, u+1, SAOFF(1,0)); LDA_H(aS0, dS0, 0, u+2); },
          { WRA_H(aS1, dS1, 1, u+1, SAOFF(1,1)); LDA_H(aS0, dS0, 1, u+2); STAGE(Bp, 0, u+2, SBOFF(0,0)); },
          VM10);
    // tile u+1 (buf1): WRA(u+2)<-aS0, LDA(u+3)->aS1, stage B1(u+2), B0(u+3)
    KTILE(1,
          NOPS,
          STAGE(Bp, 1, u+2, SBOFF(0,1)),
          { WRA_H(aS0, dS0, 0, u+2, SAOFF(0,0)); LDA_H(aS1, dS1, 0, u+3); },
          { WRA_H(aS0, dS0, 1, u+2, SAOFF(0,1)); LDA_H(aS1, dS1, 1, u+3); STAGE(Bp, 0, u+3, SBOFF(1,0)); },
          VM10);
  }
  // Peeled tile NT-2 (buf0): finish A(NT-1) writes + B1(NT-1); drain.
  KTILE(0,
        NOPS,
        STAGE(Bp, 1, NT-1, SBOFF(1,1)),
        WRA_H(aS1, dS1, 0, NT-1, SAOFF(1,0)),
        WRA_H(aS1, dS1, 1, NT-1, SAOFF(1,1)),
        VM0);
  // Peeled tile NT-1 (buf1)
  KTILE(1, NOPS, NOPS, NOPS, NOPS, NOPS);

  // C-write: output [B, Tk, V]
  const long cb = (long)bz*TK_*NV_;
#pragma unroll
  for (int i=0;i<8;++i)
#pragma unroll
    for (int j=0;j<4;++j)
#pragma unroll
      for (int g=0; g<4; ++g){
        const long gm = m0 + wr*128 + i*16 + lq*4 + g;
        const long gn = n0 + wc*64  + j*16 + lm;
        outp[cb + gm*NV_ + gn] = acc[i][j][g];
      }
}

// ---------------- row softmax (fallback path only) ----------------
__global__ __launch_bounds__(256) void softmax_k(float* __restrict__ lg, ushort* __restrict__ pb){
  const long base = (long)blockIdx.x * TV_;
  const int tid = threadIdx.x;
  const int lane = tid & 63, w = tid >> 6;
  float x[8];
  fl4 a = *(const fl4*)(lg + base + tid*8);
  fl4 b = *(const fl4*)(lg + base + tid*8 + 4);
  x[0]=a[0];x[1]=a[1];x[2]=a[2];x[3]=a[3];x[4]=b[0];x[5]=b[1];x[6]=b[2];x[7]=b[3];
  float m = x[0];
#pragma unroll
  for (int j=1;j<8;++j) m = fmaxf(m, x[j]);
#pragma unroll
  for (int off=32; off; off>>=1) m = fmaxf(m, __shfl_xor(m, off));
  __shared__ float rm[4], rs[4];
  if (lane==0) rm[w]=m;
  __syncthreads();
  m = fmaxf(fmaxf(rm[0],rm[1]), fmaxf(rm[2],rm[3]));
  float s = 0.f;
#pragma unroll
  for (int j=0;j<8;++j){ x[j] = __expf(x[j]-m); s += x[j]; }
#pragma unroll
  for (int off=32; off; off>>=1) s += __shfl_xor(s, off);
  if (lane==0) rs[w]=s;
  __syncthreads();
  s = rs[0]+rs[1]+rs[2]+rs[3];
  const float inv = 1.f/s;
  fl4 p0 = {x[0]*inv, x[1]*inv, x[2]*inv, x[3]*inv};
  fl4 p1 = {x[4]*inv, x[5]*inv, x[6]*inv, x[7]*inv};
  *(fl4*)(lg + base + tid*8)     = p0;
  *(fl4*)(lg + base + tid*8 + 4) = p1;
  *(ushort4*)(pb + base + tid*8)     = make_ushort4(f2h(p0[0]),f2h(p0[1]),f2h(p0[2]),f2h(p0[3]));
  *(ushort4*)(pb + base + tid*8 + 4) = make_ushort4(f2h(p1[0]),f2h(p1[1]),f2h(p1[2]),f2h(p1[3]));
}

extern "C" void kernel_launch(void* const* d_in, const int* in_sizes, int n_in,
                              void* d_out, int out_size, void* d_ws, size_t ws_size,
                              hipStream_t stream){
  (void)in_sizes; (void)n_in; (void)out_size;
  const float* values = (const float*)d_in[0];   // [Tv,B,V]
  const float* keys   = (const float*)d_in[2];   // [B,Tk,K]
  const float* w      = (const float*)d_in[3];   // [K,V]

  float* attn = (float*)d_out;                       // [B,Tk,Tv]
  float* outp = (float*)d_out + (long)NB_*TK_*TV_;   // [B,Tk,V]

  char* ws = (char*)d_ws;
  const long MB = 1024L*1024L;
  const bool fused = ws_size >= (size_t)(340*MB);
  const size_t LDSB = 131072;

  if (fused){
    ushort* kh   = (ushort*)(ws);                // 64MB keys fp16 (reused: v2)
    ushort* vbt  = (ushort*)(ws + 64*MB);        // 64MB vbt [B,V,Tv] fp16
    ushort* plh  = (ushort*)(ws + 128*MB);       // 64MB pl fp16
    ushort* adb  = (ushort*)(ws + 192*MB);       // 128MB shifted fp16 logits
    float*  pm   = (float*)(ws + 320*MB);        // 4MB partial max
    float*  psum = (float*)(ws + 324*MB);        // 4MB partial sum-exp
    float*  dsh2 = (float*)(ws + 328*MB);        // 4MB folded shift
    ushort* wth  = (ushort*)(ws + 332*MB);       // 2MB wT fp16
    ushort* v2   = kh;

    cvt_h_k<<<2048,256,0,stream>>>(keys, kh, (long)NB_*TK_*NK_/4);
    wtrans_k<<<dim3(32,32),dim3(32,8),0,stream>>>(w, wth);
    gemm8_k<1><<<dim3(NV_/256, TK_/256, NB_),512,LDSB,stream>>>(
        kh, wth, nullptr, plh, nullptr, nullptr,
        NV_, NK_, (long)TK_*NK_, 0L, (long)TK_*NV_);
    vboth_k<<<dim3(TV_/32, NV_/32, NB_),dim3(32,8),0,stream>>>(values, v2, vbt);
    // GEMM2: shifted fp16 logits + partials
    gemm8_k<2><<<dim3(TV_/256, TK_/256, NB_),512,LDSB,stream>>>(
        plh, v2, nullptr, adb, pm, psum,
        TV_, NV_, (long)TK_*NV_, (long)TV_*NV_, (long)TK_*TV_);
    rs_k<<<NB_*TK_/256,256,0,stream>>>(pm, psum, dsh2);
    // fused softmax-apply + PV; bx==0 also writes attn fp32
    pv2_k<<<dim3(NV_/256, TK_/256, NB_),512,LDSB,stream>>>(
        adb, vbt, dsh2, attn, outp);
  } else {
    // Fallback: exact R4 path (258MB layout)
    ushort* kh  = (ushort*)(ws);
    ushort* vbt = (ushort*)(ws + 64*MB);
    ushort* plh = (ushort*)(ws + 128*MB);
    ushort* adb = (ushort*)(ws + 128*MB);
    ushort* wth = (ushort*)(ws + 256*MB);
    ushort* v2  = kh;

    cvt_h_k<<<2048,256,0,stream>>>(keys, kh, (long)NB_*TK_*NK_/4);
    wtrans_k<<<dim3(32,32),dim3(32,8),0,stream>>>(w, wth);
    gemm8_k<1><<<dim3(NV_/256, TK_/256, NB_),512,LDSB,stream>>>(
        kh, wth, nullptr, plh, nullptr, nullptr,
        NV_, NK_, (long)TK_*NK_, 0L, (long)TK_*NV_);
    vboth_k<<<dim3(TV_/32, NV_/32, NB_),dim3(32,8),0,stream>>>(values, v2, vbt);
    gemm8_k<0><<<dim3(TV_/256, TK_/256, NB_),512,LDSB,stream>>>(
        plh, v2, attn, nullptr, nullptr, nullptr,
        TV_, NV_, (long)TK_*NV_, (long)TV_*NV_, (long)TK_*TV_);
    softmax_k<<<NB_*TK_,256,0,stream>>>(attn, adb);
    gemm8_k<0><<<dim3(NV_/256, TK_/256, NB_),512,LDSB,stream>>>(
        adb, vbt, outp, nullptr, nullptr, nullptr,
        NV_, TV_, (long)TK_*TV_, (long)NV_*TV_, (long)TK_*NV_);
  }
}

// Round 8
// 608.527 us; speedup vs baseline: 2.2237x; 1.3404x over previous
//
#include <hip/hip_runtime.h>

// Problem constants (from reference)
#define TV_ 2048
#define NB_ 16
#define NV_ 1024
#define TK_ 2048
#define NK_ 1024

typedef float    f32x4 __attribute__((ext_vector_type(4)));
typedef float    fl4   __attribute__((ext_vector_type(4)));
typedef _Float16 hfx8  __attribute__((ext_vector_type(8)));
typedef ushort   us8   __attribute__((ext_vector_type(8)));

static __device__ __forceinline__ ushort f2h(float f){
  _Float16 h = (_Float16)f;               // RN-even
  return __builtin_bit_cast(ushort, h);
}
static __device__ __forceinline__ float h2f(ushort u){
  return (float)__builtin_bit_cast(_Float16, u);
}

// ---------------- elementwise convert: fp32 -> fp16 ----------------
__global__ __launch_bounds__(256) void cvt_h_k(const float* __restrict__ x,
                                               ushort* __restrict__ y, long n4){
  long i = (long)blockIdx.x*256 + threadIdx.x;
  const long stride = (long)gridDim.x*256;
  for (; i < n4; i += stride){
    fl4 v = ((const fl4*)x)[i];
    ((ushort4*)y)[i] = make_ushort4(f2h(v[0]), f2h(v[1]), f2h(v[2]), f2h(v[3]));
  }
}

// ---------------- w [K,V] -> wT [V,K] fp16 ----------------
__global__ void wtrans_k(const float* __restrict__ w, ushort* __restrict__ wT){
  __shared__ float t[32][33];
  const int tx = threadIdx.x, ty = threadIdx.y;       // 32 x 8
  const int k0 = blockIdx.x*32, v0 = blockIdx.y*32;
#pragma unroll
  for (int r=0;r<4;++r) t[ty+8*r][tx] = w[(long)(k0+ty+8*r)*NV_ + v0+tx];
  __syncthreads();
#pragma unroll
  for (int r=0;r<4;++r)
    wT[(long)(v0+ty+8*r)*NK_ + k0+tx] = f2h(t[tx][ty+8*r]);
}

// ------- values [Tv,B,V] -> v2 [B,Tv,V] fp16 AND vbt [B,V,Tv] fp16, one read -------
__global__ void vboth_k(const float* __restrict__ vals,
                        ushort* __restrict__ v2, ushort* __restrict__ vbt){
  __shared__ float t[32][33];
  const int tx = threadIdx.x, ty = threadIdx.y;       // 32 x 8
  const int s0 = blockIdx.x*32, v0 = blockIdx.y*32, b = blockIdx.z;
#pragma unroll
  for (int r=0;r<4;++r){
    float x = vals[((long)(s0+ty+8*r)*NB_ + b)*NV_ + v0+tx];
    t[ty+8*r][tx] = x;
    v2[((long)b*TV_ + s0+ty+8*r)*NV_ + v0+tx] = f2h(x);
  }
  __syncthreads();
#pragma unroll
  for (int r=0;r<4;++r)
    vbt[((long)b*NV_ + v0+ty+8*r)*TV_ + s0+tx] = f2h(t[tx][ty+8*r]);
}

// =======================================================================
// Shared 256x256 8-phase machinery (verified R4; MFMA order bit-stable).
// =======================================================================
static __device__ __forceinline__ hfx8 ldfrag(const ushort* base, int r, int q){
  const int off = r*128 + (((q ^ (r & 7)) & 7) << 4);
  return *(const hfx8*)((const char*)base + off);
}

#define SAOFF(b,h) (((b)*2+(h))*8192)
#define SBOFF(b,h) (32768 + ((b)*2+(h))*8192)

#define STAGE(Xp, hb, t, ldsoff) do { \
  _Pragma("unroll") \
  for (int c_=0;c_<2;++c_) \
    __builtin_amdgcn_global_load_lds( \
      (const __attribute__((address_space(1))) unsigned*)((Xp) + (long)(hb)*128*K + (long)(t)*64 + soff[c_]), \
      (__attribute__((address_space(3))) unsigned*)(lds + (ldsoff) + chunk0[c_]*8), 16, 0, 0); \
} while(0)

#define VM4  asm volatile("s_waitcnt vmcnt(4)"  ::: "memory")
#define VM0  asm volatile("s_waitcnt vmcnt(0)"  ::: "memory")
#define NOPS (void)0

#define BARR() do { __builtin_amdgcn_s_barrier(); __builtin_amdgcn_sched_barrier(0); } while(0)

#define MFMA_SET(IB, JB, BREG) \
  _Pragma("unroll") for (int kk=0;kk<2;++kk) \
  _Pragma("unroll") for (int i=0;i<4;++i) \
  _Pragma("unroll") for (int j=0;j<2;++j) \
    acc[(IB)+i][(JB)+j] = __builtin_amdgcn_mfma_f32_16x16x32_f16(aR[i][kk], BREG[j][kk], acc[(IB)+i][(JB)+j], 0,0,0)

// One K-tile = 4 phases. S0..S3: stage statements; EW: end wait (vmcnt) at PH3.
#define KTILE(BUF, S0, S1, S2, S3, EW) do { \
  const ushort* sa_ = lds + SAOFF(BUF, wr); \
  const ushort* sb_ = lds + SBOFF(BUF, (wc>>1)); \
  const int brow_ = (wc&1)*64; \
  /* PH0 */ \
  _Pragma("unroll") for (int i=0;i<4;++i) _Pragma("unroll") for (int kk=0;kk<2;++kk) \
    aR[i][kk] = ldfrag(sa_, i*16+lm, lq+kk*4); \
  _Pragma("unroll") for (int j=0;j<2;++j) _Pragma("unroll") for (int kk=0;kk<2;++kk) \
    b01[j][kk] = ldfrag(sb_, brow_ + j*16 + lm, lq+kk*4); \
  S0; \
  BARR(); \
  __builtin_amdgcn_s_setprio(1); \
  MFMA_SET(0, 0, b01); \
  __builtin_amdgcn_s_setprio(0); \
  BARR(); \
  /* PH1 */ \
  _Pragma("unroll") for (int j=0;j<2;++j) _Pragma("unroll") for (int kk=0;kk<2;++kk) \
    b23[j][kk] = ldfrag(sb_, brow_ + (2+j)*16 + lm, lq+kk*4); \
  S1; \
  BARR(); \
  __builtin_amdgcn_s_setprio(1); \
  MFMA_SET(0, 2, b23); \
  __builtin_amdgcn_s_setprio(0); \
  BARR(); \
  /* PH2 */ \
  _Pragma("unroll") for (int i=0;i<4;++i) _Pragma("unroll") for (int kk=0;kk<2;++kk) \
    aR[i][kk] = ldfrag(sa_, (4+i)*16+lm, lq+kk*4); \
  S2; \
  BARR(); \
  __builtin_amdgcn_s_setprio(1); \
  MFMA_SET(4, 2, b23); \
  __builtin_amdgcn_s_setprio(0); \
  BARR(); \
  /* PH3 */ \
  S3; \
  BARR(); \
  __builtin_amdgcn_s_setprio(1); \
  MFMA_SET(4, 0, b01); \
  __builtin_amdgcn_s_setprio(0); \
  EW; \
  BARR(); \
} while(0)

// ---------------- generic GEMM ----------------
// OUTMODE: 0 = fp32 C; 1 = fp16 Ch; 2 = fp16 Ch shifted by per-wave 64-col max
//          + softmax partials (pm, ps).
// GXL = log2(grid x-size). 1D launch; bijective XCD swizzle: contiguous logical
// tiles per XCD so n-blocks sharing an A-panel co-reside on one L2 (T1).
template<int OUTMODE, int GXL>
__global__ __launch_bounds__(512, 2)
void gemm8_k(const ushort* __restrict__ A, const ushort* __restrict__ BT,
             float* __restrict__ C, ushort* __restrict__ Ch,
             float* __restrict__ pm, float* __restrict__ ps,
             int N, int K, long sA, long sB, long sC)
{
  extern __shared__ ushort lds[];

  const int tid  = threadIdx.x;
  const int lane = tid & 63;
  const int w    = tid >> 6;
  const int wr   = w >> 2;
  const int wc   = w & 3;
  const int lm   = lane & 15, lq = lane >> 4;

  // XCD swizzle decode (nwg % 8 == 0 for all our launches)
  const int bid     = blockIdx.x;
  const int logical = (bid & 7)*((int)gridDim.x >> 3) + (bid >> 3);
  const int bx      = logical & ((1<<GXL)-1);
  const int by      = (logical >> GXL) & 7;          // TK_/256 = 8 always
  const int bz      = logical >> (GXL+3);
  const long m0     = (long)by * 256;
  const long n0     = (long)bx * 256;

  const ushort* Ap = A  + (long)bz*sA + m0*K;
  const ushort* Bp = BT + (long)bz*sB + n0*K;

  int chunk0[2], soff[2];
#pragma unroll
  for (int c=0;c<2;++c){
    chunk0[c] = (w<<7) + (c<<6);
    const int idx = chunk0[c] + lane;
    const int row = idx >> 3, sl = idx & 7;
    soff[c] = row*K + ((sl ^ (row & 7)) << 3);
  }

  f32x4 acc[8][4];
#pragma unroll
  for (int i=0;i<8;++i)
#pragma unroll
    for (int j=0;j<4;++j) acc[i][j] = (f32x4){0.f,0.f,0.f,0.f};

  hfx8 aR[4][2], b01[2][2], b23[2][2];

  const int NT = K >> 6;

  STAGE(Ap, 0, 0, SAOFF(0,0));
  STAGE(Ap, 1, 0, SAOFF(0,1));
  STAGE(Bp, 0, 0, SBOFF(0,0));
  STAGE(Bp, 1, 0, SBOFF(0,1));
  STAGE(Bp, 0, 1, SBOFF(1,0));
  STAGE(Ap, 0, 1, SAOFF(1,0));
  VM4;
  BARR();

  for (int u=0; u <= NT-4; u+=2){
    KTILE(0,
          STAGE(Ap, 1, u+1, SAOFF(1,1)),
          STAGE(Bp, 1, u+1, SBOFF(1,1)),
          STAGE(Bp, 0, u+2, SBOFF(0,0)),
          STAGE(Ap, 0, u+2, SAOFF(0,0)),
          VM4);
    KTILE(1,
          STAGE(Ap, 1, u+2, SAOFF(0,1)),
          STAGE(Bp, 1, u+2, SBOFF(0,1)),
          STAGE(Bp, 0, u+3, SBOFF(1,0)),
          STAGE(Ap, 0, u+3, SAOFF(1,0)),
          VM4);
  }
  KTILE(0,
        STAGE(Ap, 1, NT-1, SAOFF(1,1)),
        STAGE(Bp, 1, NT-1, SBOFF(1,1)),
        NOPS, NOPS, VM0);
  KTILE(1, NOPS, NOPS, NOPS, NOPS, NOPS);

  const long cb = (long)bz*sC;
  if constexpr (OUTMODE == 2){
#pragma unroll
    for (int i=0;i<8;++i){
      float mts[4];
#pragma unroll
      for (int g=0; g<4; ++g){
        float mt = fmaxf(fmaxf(acc[i][0][g], acc[i][1][g]), fmaxf(acc[i][2][g], acc[i][3][g]));
#pragma unroll
        for (int off=1; off<16; off<<=1) mt = fmaxf(mt, __shfl_xor(mt, off));
        float se = 0.f;
#pragma unroll
        for (int j=0;j<4;++j) se += __expf(acc[i][j][g] - mt);
#pragma unroll
        for (int off=1; off<16; off<<=1) se += __shfl_xor(se, off);
        if (lm == 0){
          const long rg = (long)bz*TK_ + m0 + wr*128 + i*16 + lq*4 + g;
          pm[rg*32 + bx*4 + wc] = mt;
          ps[rg*32 + bx*4 + wc] = se;
        }
        mts[g] = mt;
      }
#pragma unroll
      for (int j=0;j<4;++j)
#pragma unroll
        for (int g=0; g<4; ++g){
          const long gm = m0 + wr*128 + i*16 + lq*4 + g;
          const long gn = n0 + wc*64  + j*16 + lm;
          Ch[cb + gm*N + gn] = f2h(acc[i][j][g] - mts[g]);
        }
    }
  } else {
#pragma unroll
    for (int i=0;i<8;++i)
#pragma unroll
      for (int j=0;j<4;++j)
#pragma unroll
        for (int g=0; g<4; ++g){
          const long gm = m0 + wr*128 + i*16 + lq*4 + g;
          const long gn = n0 + wc*64  + j*16 + lm;
          const long o = cb + gm*N + gn;
          if constexpr (OUTMODE == 1) Ch[o] = f2h(acc[i][j][g]);
          else                        C[o]  = acc[i][j][g];
        }
  }
}

// ---- row-stat reduce: 32 (max,sumexp) partials -> dsh2[r][p] = mt - m - ln(s) ----
__global__ __launch_bounds__(256) void rs_k(const float* __restrict__ pm,
                                            const float* __restrict__ ps,
                                            float* __restrict__ dsh2){
  const long r = (long)blockIdx.x*256 + threadIdx.x;   // 32768 rows
  float pmv[32];
  float m = -3.4e38f;
#pragma unroll
  for (int p=0;p<32;++p){ pmv[p] = pm[r*32+p]; m = fmaxf(m, pmv[p]); }
  float s = 0.f;
#pragma unroll
  for (int p=0;p<32;++p) s += ps[r*32+p] * __expf(pmv[p] - m);
  const float lg = __logf(s);
#pragma unroll
  for (int p=0;p<32;++p) dsh2[r*32+p] = pmv[p] - m - lg;
}

// ---- streaming exp pass: P = exp(h + dsh2); writes attn fp32 + P16 fp16 ----
// BW-bound (512 MB total); the 64M exps cost ~2 us of trans pipe.
__global__ __launch_bounds__(256) void pexp_k(const ushort* __restrict__ h16,
                                              const float* __restrict__ dsh2,
                                              float* __restrict__ attn,
                                              ushort* __restrict__ p16){
  const long n8 = (long)NB_*TK_*TV_/8;
  long i = (long)blockIdx.x*256 + threadIdx.x;
  const long stride = (long)gridDim.x*256;
  for (; i < n8; i += stride){
    us8 hv = ((const us8*)h16)[i];
    const long row = i >> 8;               // Tv/8 = 256 8-elem chunks per row
    const int  c8  = (int)(i & 255);
    const float d = dsh2[row*32 + (c8>>3)];
    float p[8];
#pragma unroll
    for (int e=0;e<8;++e) p[e] = __expf(h2f((ushort)hv[e]) + d);
    fl4 q0 = {p[0],p[1],p[2],p[3]}, q1 = {p[4],p[5],p[6],p[7]};
    *(fl4*)(attn + i*8)     = q0;
    *(fl4*)(attn + i*8 + 4) = q1;
    us8 o;
#pragma unroll
    for (int e=0;e<8;++e) o[e] = f2h(p[e]);
    ((us8*)p16)[i] = o;
  }
}

// ---------------- row softmax (fallback path only) ----------------
__global__ __launch_bounds__(256) void softmax_k(float* __restrict__ lg, ushort* __restrict__ pb){
  const long base = (long)blockIdx.x * TV_;
  const int tid = threadIdx.x;
  const int lane = tid & 63, w = tid >> 6;
  float x[8];
  fl4 a = *(const fl4*)(lg + base + tid*8);
  fl4 b = *(const fl4*)(lg + base + tid*8 + 4);
  x[0]=a[0];x[1]=a[1];x[2]=a[2];x[3]=a[3];x[4]=b[0];x[5]=b[1];x[6]=b[2];x[7]=b[3];
  float m = x[0];
#pragma unroll
  for (int j=1;j<8;++j) m = fmaxf(m, x[j]);
#pragma unroll
  for (int off=32; off; off>>=1) m = fmaxf(m, __shfl_xor(m, off));
  __shared__ float rm[4], rs[4];
  if (lane==0) rm[w]=m;
  __syncthreads();
  m = fmaxf(fmaxf(rm[0],rm[1]), fmaxf(rm[2],rm[3]));
  float s = 0.f;
#pragma unroll
  for (int j=0;j<8;++j){ x[j] = __expf(x[j]-m); s += x[j]; }
#pragma unroll
  for (int off=32; off; off>>=1) s += __shfl_xor(s, off);
  if (lane==0) rs[w]=s;
  __syncthreads();
  s = rs[0]+rs[1]+rs[2]+rs[3];
  const float inv = 1.f/s;
  fl4 p0 = {x[0]*inv, x[1]*inv, x[2]*inv, x[3]*inv};
  fl4 p1 = {x[4]*inv, x[5]*inv, x[6]*inv, x[7]*inv};
  *(fl4*)(lg + base + tid*8)     = p0;
  *(fl4*)(lg + base + tid*8 + 4) = p1;
  *(ushort4*)(pb + base + tid*8)     = make_ushort4(f2h(p0[0]),f2h(p0[1]),f2h(p0[2]),f2h(p0[3]));
  *(ushort4*)(pb + base + tid*8 + 4) = make_ushort4(f2h(p1[0]),f2h(p1[1]),f2h(p1[2]),f2h(p1[3]));
}

extern "C" void kernel_launch(void* const* d_in, const int* in_sizes, int n_in,
                              void* d_out, int out_size, void* d_ws, size_t ws_size,
                              hipStream_t stream){
  (void)in_sizes; (void)n_in; (void)out_size;
  const float* values = (const float*)d_in[0];   // [Tv,B,V]
  const float* keys   = (const float*)d_in[2];   // [B,Tk,K]
  const float* w      = (const float*)d_in[3];   // [K,V]

  float* attn = (float*)d_out;                       // [B,Tk,Tv]
  float* outp = (float*)d_out + (long)NB_*TK_*TV_;   // [B,Tk,V]

  char* ws = (char*)d_ws;
  const long MB = 1024L*1024L;
  const bool fused = ws_size >= (size_t)(340*MB);
  const size_t LDSB = 131072;

  if (fused){
    ushort* kh   = (ushort*)(ws);                // 64MB keys fp16 (reused: v2)
    ushort* vbt  = (ushort*)(ws + 64*MB);        // 64MB vbt [B,V,Tv] fp16
    ushort* plh  = (ushort*)(ws + 128*MB);       // 64MB pl fp16 (reused: P16 low half)
    ushort* adb  = (ushort*)(ws + 192*MB);       // 128MB shifted fp16 logits
    float*  pm   = (float*)(ws + 320*MB);        // 4MB partial max
    float*  psum = (float*)(ws + 324*MB);        // 4MB partial sum-exp
    float*  dsh2 = (float*)(ws + 328*MB);        // 4MB folded shift
    ushort* wth  = (ushort*)(ws + 332*MB);       // 2MB wT fp16
    ushort* v2   = kh;
    ushort* p16  = plh;                          // 128MB P fp16 (plh+kh... see note)
    // NOTE: p16 needs 128MB; plh is 64MB at 128..192 and adb starts at 192.
    // Use plh region ONLY if it fits: P16 = [B,Tk,Tv] fp16 = 128MB -> spans
    // 128..256MB which overlaps adb (its own input). Instead place P16 at
    // 0..128MB (kh+vbt space): kh is dead after GEMM2; vbt is still needed by
    // GEMM3! So: P16 goes to 128..192 (plh, dead after GEMM2) is too small.
    // Final: P16 at ws+0 (kh 64MB, dead after GEMM2) + we must NOT overwrite
    // vbt. 128MB needed -> kh(64) insufficient alone. Solution: put P16 in a
    // dedicated region by raising the ws threshold: 340MB layout has no free
    // 128MB. Use adb itself? pexp reads adb and writes P16 elementwise 1:1 —
    // same index i read-then-write -> IN-PLACE is safe per element.
    p16 = adb;                                   // in-place: read h, write P16

    cvt_h_k<<<2048,256,0,stream>>>(keys, kh, (long)NB_*TK_*NK_/4);
    wtrans_k<<<dim3(32,32),dim3(32,8),0,stream>>>(w, wth);
    gemm8_k<1,2><<<512,512,LDSB,stream>>>(            // GEMM1: grid (4,8,16)
        kh, wth, nullptr, plh, nullptr, nullptr,
        NV_, NK_, (long)TK_*NK_, 0L, (long)TK_*NV_);
    vboth_k<<<dim3(TV_/32, NV_/32, NB_),dim3(32,8),0,stream>>>(values, v2, vbt);
    // GEMM2: shifted fp16 logits + partials; grid (8,8,16)
    gemm8_k<2,3><<<1024,512,LDSB,stream>>>(
        plh, v2, nullptr, adb, pm, psum,
        TV_, NV_, (long)TK_*NV_, (long)TV_*NV_, (long)TK_*TV_);
    rs_k<<<NB_*TK_/256,256,0,stream>>>(pm, psum, dsh2);
    // exp pass: attn fp32 + P16 fp16 (in-place over adb)
    pexp_k<<<2048,256,0,stream>>>(adb, dsh2, attn, p16);
    // GEMM3: out = P16 * vbt^T; grid (4,8,16)
    gemm8_k<0,2><<<512,512,LDSB,stream>>>(
        p16, vbt, outp, nullptr, nullptr, nullptr,
        NV_, TV_, (long)TK_*TV_, (long)NV_*TV_, (long)TK_*NV_);
  } else {
    // Fallback: R4 path (258MB layout), swizzled GEMMs
    ushort* kh  = (ushort*)(ws);
    ushort* vbt = (ushort*)(ws + 64*MB);
    ushort* plh = (ushort*)(ws + 128*MB);
    ushort* adb = (ushort*)(ws + 128*MB);
    ushort* wth = (ushort*)(ws + 256*MB);
    ushort* v2  = kh;

    cvt_h_k<<<2048,256,0,stream>>>(keys, kh, (long)NB_*TK_*NK_/4);
    wtrans_k<<<dim3(32,32),dim3(32,8),0,stream>>>(w, wth);
    gemm8_k<1,2><<<512,512,LDSB,stream>>>(
        kh, wth, nullptr, plh, nullptr, nullptr,
        NV_, NK_, (long)TK_*NK_, 0L, (long)TK_*NV_);
    vboth_k<<<dim3(TV_/32, NV_/32, NB_),dim3(32,8),0,stream>>>(values, v2, vbt);
    gemm8_k<0,3><<<1024,512,LDSB,stream>>>(
        plh, v2, attn, nullptr, nullptr, nullptr,
        TV_, NV_, (long)TK_*NV_, (long)TV_*NV_, (long)TK_*TV_);
    softmax_k<<<NB_*TK_,256,0,stream>>>(attn, adb);
    gemm8_k<0,2><<<512,512,LDSB,stream>>>(
        adb, vbt, outp, nullptr, nullptr, nullptr,
        NV_, TV_, (long)TK_*TV_, (long)NV_*TV_, (long)TK_*NV_);
  }
}